// Round 6
// baseline (38.034 us; speedup 1.0000x reference)
//
#include <hip/hip_runtime.h>
#include <math.h>

#define TPB  512
#define NBLK 32
#define CAP  1024          // LDS candidate capacity (expected ~40 used)
#define BMW_MAX 2048       // bitmap words -> supports n <= 65536
#define NW   (TPB / 64)

typedef unsigned long long ull;

__device__ __forceinline__ ull umin64(ull a, ull b) { return a < b ? a : b; }
__device__ __forceinline__ ull umax64(ull a, ull b) { return a > b ? a : b; }

// Branchless order-statistic merge of two ascending 5-lists of 64-bit keys.
// Key = (dist_bits << 32) | p. obs_idx is sorted, so ordering/tie-break by
// cell index p is exactly equivalent to the reference's ordering by j
// (monotone bijection) -> exact jax.lax.top_k semantics.
__device__ __forceinline__ void merge5u(ull& a0, ull& a1, ull& a2, ull& a3, ull& a4,
                                        ull b0, ull b1, ull b2, ull b3, ull b4) {
    ull m0 = umin64(a0, b0);
    ull m1 = umin64(umin64(a1, b1), umax64(a0, b0));
    ull m2 = umin64(umin64(a2, b2), umin64(umax64(a0, b1), umax64(a1, b0)));
    ull m3 = umin64(umin64(a3, b3),
                    umin64(umin64(umax64(a0, b2), umax64(a1, b1)), umax64(a2, b0)));
    ull m4 = umin64(umin64(a4, b4),
                    umin64(umin64(umax64(a0, b3), umax64(a1, b2)),
                           umin64(umax64(a2, b1), umax64(a3, b0))));
    a0 = m0; a1 = m1; a2 = m2; a3 = m3; a4 = m4;
}

__device__ __forceinline__ void insert5u(ull key, ull& k0, ull& k1, ull& k2, ull& k3, ull& k4) {
    if (key < k4) {
        k4 = key;
        ull t;
        if (k4 < k3) { t = k3; k3 = k4; k4 = t; }
        if (k3 < k2) { t = k2; k2 = k3; k3 = t; }
        if (k2 < k1) { t = k1; k1 = k2; k2 = t; }
        if (k1 < k0) { t = k0; k0 = k1; k1 = t; }
    }
}

#define BFLYU(kk0,kk1,kk2,kk3,kk4,WIDTH)                            \
    for (int mask_ = 1; mask_ < (WIDTH); mask_ <<= 1) {             \
        ull b0_ = __shfl_xor(kk0, mask_, 64);                       \
        ull b1_ = __shfl_xor(kk1, mask_, 64);                       \
        ull b2_ = __shfl_xor(kk2, mask_, 64);                       \
        ull b3_ = __shfl_xor(kk3, mask_, 64);                       \
        ull b4_ = __shfl_xor(kk4, mask_, 64);                       \
        merge5u(kk0, kk1, kk2, kk3, kk4, b0_, b1_, b2_, b3_, b4_);  \
    }

// ---------------------------------------------------------------------------
// One kernel, NBLK independent blocks. Each block redundantly computes the
// exact scalar v (coalesced strided passes), then writes its disjoint slice
// of out = missing ? v : X. No workspace, no cross-block communication.
//
// Pass A computes iteration 1 exactly (v0=0: top-5 of (x^2, p) over observed)
// AND the exact r0^2 (5th-smallest observed x^2). Reachability bound: iter-1
// picks |x|<=r0 -> |v1|<=r0; d5(v1)<=2r0 -> iter-2 picks |x|<=3r0 -> |v2|<=3r0;
// d5(v2)<=4r0 -> iter-3 picks |x|<=7r0. Candidate filter x^2 <= 64*r0^2
// keeps a strict superset; overflow/underflow -> exact full-scan fallback.
// ---------------------------------------------------------------------------
__global__ void __launch_bounds__(TPB) knn_one_kernel(
    const float* __restrict__ X, const int* __restrict__ miss_idx,
    float* __restrict__ out, int n, int n_miss)
{
    __shared__ unsigned bm[BMW_MAX];     // missing bitmap (4 KB @ n=32768)
    __shared__ uint2    cand[CAP];       // (x_bits, p)
    __shared__ int      cnt_sh;
    __shared__ ull      sku[NW * 5];
    __shared__ float    v_sh, thr_sh;

    const int tid  = threadIdx.x;
    const int b    = blockIdx.x;
    const int wid  = tid >> 6;
    const int lane = tid & 63;
    const int bmw  = (n + 31) >> 5;
    const int n4   = n >> 2;

    // ---- bitmap of missing cells ----
    for (int w = tid; w < bmw; w += TPB) bm[w] = 0u;
    if (tid == 0) cnt_sh = 0;
    __syncthreads();
    for (int e = tid; e < n_miss; e += TPB) {
        int p = miss_idx[e];
        atomicOr(&bm[p >> 5], 1u << (p & 31));
    }
    __syncthreads();

    // ---- pass A (== iteration 1): top-5 of (x^2, p), coalesced strided ----
    ull k0 = ~0ull, k1 = ~0ull, k2 = ~0ull, k3 = ~0ull, k4 = ~0ull;
    for (int g = tid; g < n4; g += TPB) {
        float4 xx = reinterpret_cast<const float4*>(X)[g];
        int p0 = g << 2;                                   // p0 % 4 == 0 -> 4 bits in one word
        unsigned bits = (bm[p0 >> 5] >> (p0 & 31)) & 0xFu;
        float c4[4] = {xx.x, xx.y, xx.z, xx.w};
#pragma unroll
        for (int c = 0; c < 4; ++c) {
            if (!(bits & (1u << c))) {
                float x = c4[c];
                insert5u(((ull)__float_as_uint(x * x) << 32) | (unsigned)(p0 + c),
                         k0, k1, k2, k3, k4);
            }
        }
    }
    for (int p = (n4 << 2) + tid; p < n; p += TPB) {       // scalar tail
        if (!((bm[p >> 5] >> (p & 31)) & 1u)) {
            float x = X[p];
            insert5u(((ull)__float_as_uint(x * x) << 32) | (unsigned)p,
                     k0, k1, k2, k3, k4);
        }
    }
    BFLYU(k0, k1, k2, k3, k4, 64)
    if (lane == 0) {
        sku[wid * 5 + 0] = k0; sku[wid * 5 + 1] = k1; sku[wid * 5 + 2] = k2;
        sku[wid * 5 + 3] = k3; sku[wid * 5 + 4] = k4;
    }
    __syncthreads();
    if (wid == 0) {
        ull g0 = ~0ull, g1 = ~0ull, g2 = ~0ull, g3 = ~0ull, g4 = ~0ull;
        if (lane < NW) {
            g0 = sku[lane * 5 + 0]; g1 = sku[lane * 5 + 1]; g2 = sku[lane * 5 + 2];
            g3 = sku[lane * 5 + 3]; g4 = sku[lane * 5 + 4];
        }
        BFLYU(g0, g1, g2, g3, g4, NW)
        // winner values: direct X[p] loads (L1/L2-hot), 5 parallel lanes
        float x5 = 0.0f;
        if (lane < 5) {
            ull key = (lane == 0) ? g0 : (lane == 1) ? g1 : (lane == 2) ? g2
                     : (lane == 3) ? g3 : g4;
            if (key != ~0ull) x5 = X[(unsigned)(key & 0xFFFFFFFFull)];
        }
        float x0 = __shfl(x5, 0, 64), x1 = __shfl(x5, 1, 64), x2 = __shfl(x5, 2, 64),
              x3 = __shfl(x5, 3, 64), x4v = __shfl(x5, 4, 64);
        if (lane == 0) {
            // ascending (dist, p) order == reference sum order
            float s = x0; s += x1; s += x2; s += x3; s += x4v;
            v_sh = s * 0.2f;
            float r02 = __uint_as_float((unsigned)(g4 >> 32));   // exact 5th-smallest x^2
            thr_sh = 64.0f * r02;          // (8*r0)^2; degenerate -> NaN -> C=0 -> fallback
        }
    }
    __syncthreads();
    float v = v_sh;
    const float thr = thr_sh;

    // ---- pass B: collect candidates (x^2 <= 64*r0^2), L1/L2-hot reads ----
    for (int g = tid; g < n4; g += TPB) {
        float4 xx = reinterpret_cast<const float4*>(X)[g];
        int p0 = g << 2;
        unsigned bits = (bm[p0 >> 5] >> (p0 & 31)) & 0xFu;
        float c4[4] = {xx.x, xx.y, xx.z, xx.w};
#pragma unroll
        for (int c = 0; c < 4; ++c) {
            if (!(bits & (1u << c))) {
                float x = c4[c];
                if (x * x <= thr) {
                    int s = atomicAdd(&cnt_sh, 1);
                    if (s < CAP) cand[s] = make_uint2(__float_as_uint(x), (unsigned)(p0 + c));
                }
            }
        }
    }
    for (int p = (n4 << 2) + tid; p < n; p += TPB) {
        if (!((bm[p >> 5] >> (p & 31)) & 1u)) {
            float x = X[p];
            if (x * x <= thr) {
                int s = atomicAdd(&cnt_sh, 1);
                if (s < CAP) cand[s] = make_uint2(__float_as_uint(x), (unsigned)p);
            }
        }
    }
    __syncthreads();
    const int  C    = cnt_sh;
    const bool fast = (C >= 5) && (C <= CAP);   // stored candidate SET is
    // schedule-independent when C<=CAP (every passing element stored exactly
    // once); top-5 selection is set-based -> deterministic output.

    // ---- iterations 2 and 3 ----
    for (int it = 0; it < 2; ++it) {
        ull q0 = ~0ull, q1 = ~0ull, q2 = ~0ull, q3 = ~0ull, q4 = ~0ull;
        if (fast) {
            for (int e = tid; e < C; e += TPB) {
                uint2 ce = cand[e];
                float x  = __uint_as_float(ce.x);
                float df = v - x;
                insert5u(((ull)__float_as_uint(df * df) << 32) | (ull)ce.y,
                         q0, q1, q2, q3, q4);
            }
        } else {
            // exact full-scan fallback (coalesced; never expected on this data)
            for (int g = tid; g < n4; g += TPB) {
                float4 xx = reinterpret_cast<const float4*>(X)[g];
                int p0 = g << 2;
                unsigned bits = (bm[p0 >> 5] >> (p0 & 31)) & 0xFu;
                float c4[4] = {xx.x, xx.y, xx.z, xx.w};
#pragma unroll
                for (int c = 0; c < 4; ++c) {
                    if (!(bits & (1u << c))) {
                        float df = v - c4[c];
                        insert5u(((ull)__float_as_uint(df * df) << 32) | (unsigned)(p0 + c),
                                 q0, q1, q2, q3, q4);
                    }
                }
            }
            for (int p = (n4 << 2) + tid; p < n; p += TPB) {
                if (!((bm[p >> 5] >> (p & 31)) & 1u)) {
                    float df = v - X[p];
                    insert5u(((ull)__float_as_uint(df * df) << 32) | (unsigned)p,
                             q0, q1, q2, q3, q4);
                }
            }
        }
        BFLYU(q0, q1, q2, q3, q4, 64)
        if (lane == 0) {
            sku[wid * 5 + 0] = q0; sku[wid * 5 + 1] = q1; sku[wid * 5 + 2] = q2;
            sku[wid * 5 + 3] = q3; sku[wid * 5 + 4] = q4;
        }
        __syncthreads();
        if (wid == 0) {
            ull g0 = ~0ull, g1 = ~0ull, g2 = ~0ull, g3 = ~0ull, g4 = ~0ull;
            if (lane < NW) {
                g0 = sku[lane * 5 + 0]; g1 = sku[lane * 5 + 1]; g2 = sku[lane * 5 + 2];
                g3 = sku[lane * 5 + 3]; g4 = sku[lane * 5 + 4];
            }
            BFLYU(g0, g1, g2, g3, g4, NW)
            float x5 = 0.0f;
            if (lane < 5) {
                ull key = (lane == 0) ? g0 : (lane == 1) ? g1 : (lane == 2) ? g2
                         : (lane == 3) ? g3 : g4;
                if (key != ~0ull) x5 = X[(unsigned)(key & 0xFFFFFFFFull)];
            }
            float x0 = __shfl(x5, 0, 64), x1 = __shfl(x5, 1, 64), x2 = __shfl(x5, 2, 64),
                  x3 = __shfl(x5, 3, 64), x4v = __shfl(x5, 4, 64);
            if (lane == 0) {
                float s = x0; s += x1; s += x2; s += x3; s += x4v;
                v_sh = s * 0.2f;
            }
        }
        __syncthreads();   // orders: wave0's sku reads (above) before next iter's writes
        v = v_sh;
    }

    // ---- fused output: block-disjoint slices, out = missing ? v : X ----
    const int cpb = (n4 + NBLK - 1) / NBLK;
    const int ge  = min(n4, (b + 1) * cpb);
    for (int g = b * cpb + tid; g < ge; g += TPB) {
        int p0 = g << 2;
        float4 xx = reinterpret_cast<const float4*>(X)[g];
        unsigned bits = (bm[p0 >> 5] >> (p0 & 31)) & 0xFu;
        float4 yy;
        yy.x = (bits & 1u) ? v : xx.x;
        yy.y = (bits & 2u) ? v : xx.y;
        yy.z = (bits & 4u) ? v : xx.z;
        yy.w = (bits & 8u) ? v : xx.w;
        reinterpret_cast<float4*>(out)[g] = yy;
    }
    if (b == NBLK - 1) {
        for (int p = (n4 << 2) + tid; p < n; p += TPB) {
            bool miss = (bm[p >> 5] >> (p & 31)) & 1u;
            out[p] = miss ? v : X[p];
        }
    }
}

extern "C" void kernel_launch(void* const* d_in, const int* in_sizes, int n_in,
                              void* d_out, int out_size, void* d_ws, size_t ws_size,
                              hipStream_t stream) {
    const float* X        = (const float*)d_in[0];
    const int*   miss_idx = (const int*)d_in[1];
    float*       out      = (float*)d_out;

    const int n_miss = in_sizes[1];
    const int n      = out_size;          // 32768 <= BMW_MAX*32

    knn_one_kernel<<<NBLK, TPB, 0, stream>>>(X, miss_idx, out, n, n_miss);
}